// Round 1
// baseline (457.984 us; speedup 1.0000x reference)
//
#include <hip/hip_runtime.h>
#include <math.h>

namespace {
constexpr int Cc = 256;
constexpr int Hh = 128;
constexpr int Ww = 256;
constexpr int HW = Hh * Ww;          // 32768
constexpr int CHW = Cc * HW;         // 8388608
constexpr int MAXN = 5;
constexpr int PIX_PER_BLK = 64;
constexpr int BLOCKS_PER_BATCH = HW / PIX_PER_BLK;  // 512
}

// record_len is a module constant in the reference: {5,4,3,2}, starts {0,5,9,12}.
// N = 5 - b, start s = 5b - b(b-1)/2.

__global__ __launch_bounds__(256, 4)
void atten_comm_kernel(const float* __restrict__ x,
                       const float* __restrict__ tmat,
                       float* __restrict__ out)
{
    const int lane = threadIdx.x & 63;          // pixel within block
    const int wv   = threadIdx.x >> 6;          // channel quarter 0..3
    const int b    = blockIdx.x >> 9;           // 512 blocks per batch
    const int pblk = blockIdx.x & (BLOCKS_PER_BATCH - 1);
    const int p    = pblk * PIX_PER_BLK + lane;
    const int h    = p >> 8;                    // p / W
    const int w    = p & (Ww - 1);
    const int N    = 5 - b;                     // wave-uniform
    const int s    = 5 * b - (b * (b - 1)) / 2;

    const float gx = -1.0f + 2.0f * (float)w / (float)(Ww - 1);
    const float gy = -1.0f + 2.0f * (float)h / (float)(Hh - 1);

    // Per-agent bilinear taps: 4 offsets + 4 weights (validity folded into weight).
    int   off[MAXN][4];
    float wt [MAXN][4];
#pragma unroll
    for (int j = 0; j < MAXN; ++j) {
        if (j < N) {
            // t = pairwise[b,0,j]: rows (0,1), cols (0,1,3), with reference scaling
            const float* Mp = tmat + ((size_t)(b * 25 + j)) * 16;
            const float a00 = Mp[0];
            const float a01 = Mp[1] * ((float)Hh / (float)Ww);
            const float a02 = Mp[3] * (2.0f / (4.0f * 0.4f * (float)Ww));
            const float a10 = Mp[4] * ((float)Ww / (float)Hh);
            const float a11 = Mp[5];
            const float a12 = Mp[7] * (2.0f / (4.0f * 0.4f * (float)Hh));
            const float px = (a00 * gx + a01 * gy + a02 + 1.0f) * 0.5f * (float)(Ww - 1);
            const float py = (a10 * gx + a11 * gy + a12 + 1.0f) * 0.5f * (float)(Hh - 1);
            const float x0f = floorf(px), y0f = floorf(py);
            const float fx = px - x0f, fy = py - y0f;
            const int x0 = (int)x0f, y0 = (int)y0f;
            const float tww[4] = { (1.f - fx) * (1.f - fy), fx * (1.f - fy),
                                   (1.f - fx) * fy,         fx * fy };
#pragma unroll
            for (int t = 0; t < 4; ++t) {
                const int xx = x0 + (t & 1);
                const int yy = y0 + (t >> 1);
                const bool valid = (xx >= 0) & (xx < Ww) & (yy >= 0) & (yy < Hh);
                const int xc = min(max(xx, 0), Ww - 1);
                const int yc = min(max(yy, 0), Hh - 1);
                off[j][t] = yc * Ww + xc;
                wt[j][t]  = valid ? tww[t] : 0.0f;
            }
        } else {
#pragma unroll
            for (int t = 0; t < 4; ++t) { off[j][t] = 0; wt[j][t] = 0.f; }
        }
    }

    const float* xb = x + (size_t)s * CHW;
    const int c0 = wv * (Cc / 4);

    // ---- pass 1: partial dot products over this wave's 64 channels ----
    float dot[MAXN] = {0.f, 0.f, 0.f, 0.f, 0.f};
    for (int c = c0; c < c0 + Cc / 4; ++c) {
        const float* pc = xb + (size_t)c * HW;
        const float f0 = wt[0][0] * pc[off[0][0]] + wt[0][1] * pc[off[0][1]]
                       + wt[0][2] * pc[off[0][2]] + wt[0][3] * pc[off[0][3]];
        dot[0] = fmaf(f0, f0, dot[0]);
#pragma unroll
        for (int j = 1; j < MAXN; ++j) {
            if (j < N) {
                const float* pj = pc + (size_t)j * CHW;
                const float fj = wt[j][0] * pj[off[j][0]] + wt[j][1] * pj[off[j][1]]
                               + wt[j][2] * pj[off[j][2]] + wt[j][3] * pj[off[j][3]];
                dot[j] = fmaf(f0, fj, dot[j]);
            }
        }
    }

    // ---- cross-wave reduce (4 partials per (j,pixel)), conflict-free layout ----
    __shared__ float dl[4][MAXN][PIX_PER_BLK];
#pragma unroll
    for (int j = 0; j < MAXN; ++j) dl[wv][j][lane] = dot[j];
    __syncthreads();

    float e[MAXN];
    {
        float sc[MAXN];
#pragma unroll
        for (int j = 0; j < MAXN; ++j)
            sc[j] = (dl[0][j][lane] + dl[1][j][lane] + dl[2][j][lane] + dl[3][j][lane])
                    * (1.0f / 16.0f);   // * 1/sqrt(C)
        float m = sc[0];
#pragma unroll
        for (int j = 1; j < MAXN; ++j) if (j < N) m = fmaxf(m, sc[j]);
        float sum = 0.f;
#pragma unroll
        for (int j = 0; j < MAXN; ++j) {
            e[j] = (j < N) ? expf(sc[j] - m) : 0.f;
            sum += e[j];
        }
        const float inv = 1.0f / sum;
#pragma unroll
        for (int j = 0; j < MAXN; ++j) e[j] *= inv;
    }

    // ---- pass 2: weighted resample and write ----
    float* ob = out + (size_t)b * CHW + p;
    for (int c = c0; c < c0 + Cc / 4; ++c) {
        const float* pc = xb + (size_t)c * HW;
        float acc = 0.f;
#pragma unroll
        for (int j = 0; j < MAXN; ++j) {
            if (j < N) {
                const float* pj = pc + (size_t)j * CHW;
                const float fj = wt[j][0] * pj[off[j][0]] + wt[j][1] * pj[off[j][1]]
                               + wt[j][2] * pj[off[j][2]] + wt[j][3] * pj[off[j][3]];
                acc = fmaf(e[j], fj, acc);
            }
        }
        ob[(size_t)c * HW] = acc;
    }
}

extern "C" void kernel_launch(void* const* d_in, const int* in_sizes, int n_in,
                              void* d_out, int out_size, void* d_ws, size_t ws_size,
                              hipStream_t stream) {
    const float* x    = (const float*)d_in[0];
    // d_in[1] = rm (unused by the reference's output), d_in[2] = record_len (constant)
    const float* tmat = (const float*)d_in[3];
    float* out = (float*)d_out;
    dim3 grid(4 * BLOCKS_PER_BATCH);
    dim3 block(256);
    hipLaunchKernelGGL(atten_comm_kernel, grid, block, 0, stream, x, tmat, out);
}

// Round 2
// 304.738 us; speedup vs baseline: 1.5029x; 1.5029x over previous
//
#include <hip/hip_runtime.h>
#include <hip/hip_bf16.h>
#include <math.h>

namespace {
constexpr int Cc = 256;
constexpr int Hh = 128;
constexpr int Ww = 256;
constexpr int HW  = Hh * Ww;        // 32768
constexpr int CHW = Cc * HW;        // 8388608
constexpr int P    = 32;            // pixels per block
constexpr int NTHR = 512;           // 8 waves
constexpr int CPG  = 16;            // channels per thread (256 / (NTHR/P))
constexpr int TILES = HW / P;       // 1024 tiles per batch
}

__device__ __forceinline__ unsigned short f2bf(float f) {
    __hip_bfloat16 h = __float2bfloat16(f);      // round-to-nearest
    return __builtin_bit_cast(unsigned short, h);
}
__device__ __forceinline__ float bf2f(unsigned short u) {
    return __uint_as_float(((unsigned int)u) << 16);
}
__device__ __forceinline__ float gather4(const float* __restrict__ pc,
                                         const int* o, const float* wgt) {
    return wgt[0] * pc[o[0]] + wgt[1] * pc[o[1]]
         + wgt[2] * pc[o[2]] + wgt[3] * pc[o[3]];
}

// record_len is a module constant: {5,4,3,2} -> N = 5-b, start s = 5b - b(b-1)/2.

__global__ __launch_bounds__(NTHR, 4)
void atten_fused(const float* __restrict__ x,
                 const float* __restrict__ tmat,
                 float* __restrict__ out)
{
    __shared__ ushort4 feat[Cc][P];   // bf16-packed agents 1..4, 64 KB
    __shared__ float   dl[8][5][P];   // per-wave partial dots, 5 KB

    const int tid  = threadIdx.x;
    const int lane = tid & 63;
    const int wv   = tid >> 6;
    const int pix  = lane & (P - 1);
    const int slot = lane >> 5;          // 0/1
    const int g    = wv * 2 + slot;      // channel group 0..15

    const int b    = blockIdx.x >> 10;        // batch-major: heavy (N=5) first
    const int tile = blockIdx.x & (TILES - 1);
    const int p    = tile * P + pix;
    const int h    = p >> 8;
    const int w    = p & (Ww - 1);
    const int N    = 5 - b;                   // block-uniform
    const int s    = 5 * b - (b * (b - 1)) / 2;

    const float gx = -1.0f + 2.0f * (float)w / (float)(Ww - 1);
    const float gy = -1.0f + 2.0f * (float)h / (float)(Hh - 1);

    // Per-agent bilinear taps: 4 offsets + 4 weights (validity folded into weight).
    int   off[5][4];
    float wt [5][4];
#pragma unroll
    for (int j = 0; j < 5; ++j) {
        if (j < N) {
            const float* Mp = tmat + ((size_t)(b * 25 + j)) * 16;
            const float a00 = Mp[0];
            const float a01 = Mp[1] * ((float)Hh / (float)Ww);
            const float a02 = Mp[3] * (2.0f / (4.0f * 0.4f * (float)Ww));
            const float a10 = Mp[4] * ((float)Ww / (float)Hh);
            const float a11 = Mp[5];
            const float a12 = Mp[7] * (2.0f / (4.0f * 0.4f * (float)Hh));
            const float px = (a00 * gx + a01 * gy + a02 + 1.0f) * 0.5f * (float)(Ww - 1);
            const float py = (a10 * gx + a11 * gy + a12 + 1.0f) * 0.5f * (float)(Hh - 1);
            const float x0f = floorf(px), y0f = floorf(py);
            const float fx = px - x0f, fy = py - y0f;
            const int x0 = (int)x0f, y0 = (int)y0f;
            const float tww[4] = { (1.f - fx) * (1.f - fy), fx * (1.f - fy),
                                   (1.f - fx) * fy,         fx * fy };
#pragma unroll
            for (int t = 0; t < 4; ++t) {
                const int xx = x0 + (t & 1);
                const int yy = y0 + (t >> 1);
                const bool valid = (xx >= 0) & (xx < Ww) & (yy >= 0) & (yy < Hh);
                const int xc = min(max(xx, 0), Ww - 1);
                const int yc = min(max(yy, 0), Hh - 1);
                off[j][t] = yc * Ww + xc;
                wt[j][t]  = valid ? tww[t] : 0.0f;
            }
        } else {
#pragma unroll
            for (int t = 0; t < 4; ++t) { off[j][t] = 0; wt[j][t] = 0.f; }
        }
    }

    const float* xb = x + (size_t)s * CHW;
    const int cbase = g * CPG;

    // ---- pass 1: gather once; f0 -> registers, agents 1..4 -> LDS bf16 ----
    float f0[CPG];
    float d0 = 0.f, d1 = 0.f, d2 = 0.f, d3 = 0.f, d4 = 0.f;
#pragma unroll
    for (int k = 0; k < CPG; ++k) {
        const int c = cbase + k;
        const float* pc = xb + (size_t)c * HW;
        const float v0 = gather4(pc, off[0], wt[0]);
        f0[k] = v0;
        d0 = fmaf(v0, v0, d0);
        ushort4 pk = {0, 0, 0, 0};
        if (N > 1) { const float v = gather4(pc + (size_t)1 * CHW, off[1], wt[1]); d1 = fmaf(v0, v, d1); pk.x = f2bf(v); }
        if (N > 2) { const float v = gather4(pc + (size_t)2 * CHW, off[2], wt[2]); d2 = fmaf(v0, v, d2); pk.y = f2bf(v); }
        if (N > 3) { const float v = gather4(pc + (size_t)3 * CHW, off[3], wt[3]); d3 = fmaf(v0, v, d3); pk.z = f2bf(v); }
        if (N > 4) { const float v = gather4(pc + (size_t)4 * CHW, off[4], wt[4]); d4 = fmaf(v0, v, d4); pk.w = f2bf(v); }
        feat[c][pix] = pk;
    }

    // ---- dot reduce: slot pair via shuffle, then 8 waves via LDS ----
    float dj[5] = {d0, d1, d2, d3, d4};
#pragma unroll
    for (int j = 0; j < 5; ++j) dj[j] += __shfl_xor(dj[j], 32);
    if (slot == 0) {
#pragma unroll
        for (int j = 0; j < 5; ++j) dl[wv][j][pix] = dj[j];
    }
    __syncthreads();

    // ---- softmax (each thread for its own pixel; broadcast LDS reads) ----
    float e[5];
    {
        float sc[5];
#pragma unroll
        for (int j = 0; j < 5; ++j) {
            float t = 0.f;
#pragma unroll
            for (int wvi = 0; wvi < 8; ++wvi) t += dl[wvi][j][pix];
            sc[j] = t * (1.0f / 16.0f);   // * 1/sqrt(C)
        }
        float m = sc[0];
#pragma unroll
        for (int j = 1; j < 5; ++j) if (j < N) m = fmaxf(m, sc[j]);
        float sum = 0.f;
#pragma unroll
        for (int j = 0; j < 5; ++j) { e[j] = (j < N) ? expf(sc[j] - m) : 0.f; sum += e[j]; }
        const float inv = 1.0f / sum;
#pragma unroll
        for (int j = 0; j < 5; ++j) e[j] *= inv;
    }

    // ---- pass 2: weighted sum from registers + LDS, streamed out ----
    float* ob = out + (size_t)b * CHW + p;
#pragma unroll
    for (int k = 0; k < CPG; ++k) {
        const int c = cbase + k;
        const ushort4 u = feat[c][pix];
        float acc = e[0] * f0[k];
        acc = fmaf(e[1], bf2f(u.x), acc);
        acc = fmaf(e[2], bf2f(u.y), acc);
        acc = fmaf(e[3], bf2f(u.z), acc);
        acc = fmaf(e[4], bf2f(u.w), acc);
        __builtin_nontemporal_store(acc, ob + (size_t)c * HW);
    }
}

extern "C" void kernel_launch(void* const* d_in, const int* in_sizes, int n_in,
                              void* d_out, int out_size, void* d_ws, size_t ws_size,
                              hipStream_t stream) {
    const float* x    = (const float*)d_in[0];
    // d_in[1] = rm (unused by the reference output), d_in[2] = record_len (constant)
    const float* tmat = (const float*)d_in[3];
    float* out = (float*)d_out;
    dim3 grid(4 * TILES);
    dim3 block(NTHR);
    hipLaunchKernelGGL(atten_fused, grid, block, 0, stream, x, tmat, out);
}

// Round 4
// 258.775 us; speedup vs baseline: 1.7698x; 1.1776x over previous
//
#include <hip/hip_runtime.h>
#include <hip/hip_bf16.h>
#include <math.h>

namespace {
constexpr int Cc = 256;
constexpr int Hh = 128;
constexpr int Ww = 256;
constexpr int HW  = Hh * Ww;        // 32768
constexpr int CHW = Cc * HW;        // 8388608
constexpr int P     = 16;           // pixels per block
constexpr int NTHR  = 512;          // 8 waves; 32 channel groups
constexpr int CPG   = 8;            // channels per thread
constexpr int TILES = HW / P;       // 2048 tiles per batch
}

struct __attribute__((packed)) F2 { float x, y; };   // 4B-aligned pair load

__device__ __forceinline__ unsigned short f2bf(float f) {
    __hip_bfloat16 h = __float2bfloat16(f);
    return __builtin_bit_cast(unsigned short, h);
}
__device__ __forceinline__ float bf2f(unsigned short u) {
    return __uint_as_float(((unsigned int)u) << 16);
}

// record_len module constant {5,4,3,2}: N = 5-b, start s = 5b - b(b-1)/2.
// pairwise_t_matrix[b,0,0] is exactly identity (M[:,i,i]=eye) -> agent 0 = direct load.

__global__ __launch_bounds__(NTHR, 4)
void atten_fused(const float* __restrict__ x,
                 const float* __restrict__ tmat,
                 float* __restrict__ out)
{
    __shared__ ushort4 feat[Cc][P + 1];   // bf16 agents 1..4, thread-private, ~34.8 KB
    __shared__ float   dl[8][5][P];       // per-wave partial dots, 2.5 KB

    const int tid  = threadIdx.x;
    const int lane = tid & 63;
    const int wv   = tid >> 6;
    const int pix  = lane & (P - 1);
    const int sub  = lane >> 4;             // 0..3
    const int g    = wv * 4 + sub;          // channel group 0..31
    const int cbase = g * CPG;

    const int b    = blockIdx.x >> 11;      // TILES = 2048 per batch
    const int tile = blockIdx.x & (TILES - 1);
    const int p    = tile * P + pix;        // 16 consecutive pixels in one row
    const int h    = p >> 8;
    const int w    = p & (Ww - 1);
    const int N    = 5 - b;                 // block-uniform
    const int s    = 5 * b - (b * (b - 1)) / 2;

    const float gx = -1.0f + 2.0f * (float)w / (float)(Ww - 1);
    const float gy = -1.0f + 2.0f * (float)h / (float)(Hh - 1);

    // Agents 1..4: row-factored bilinear taps. One clamped base offset + 4 weights.
    int   offp[4];
    float wxA[4], wxB[4], wyA[4], wyB[4];
#pragma unroll
    for (int a = 0; a < 4; ++a) {
        offp[a] = 0; wxA[a] = 0.f; wxB[a] = 0.f; wyA[a] = 0.f; wyB[a] = 0.f;
        if (a < N - 1) {
            const int j = a + 1;
            const float* Mp = tmat + (size_t)(b * 25 + j) * 16;
            const float a00 = Mp[0];
            const float a01 = Mp[1] * ((float)Hh / (float)Ww);
            const float a02 = Mp[3] * (2.0f / (4.0f * 0.4f * (float)Ww));
            const float a10 = Mp[4] * ((float)Ww / (float)Hh);
            const float a11 = Mp[5];
            const float a12 = Mp[7] * (2.0f / (4.0f * 0.4f * (float)Hh));
            const float px = (a00 * gx + a01 * gy + a02 + 1.0f) * 0.5f * (float)(Ww - 1);
            const float py = (a10 * gx + a11 * gy + a12 + 1.0f) * 0.5f * (float)(Hh - 1);
            const float x0f = floorf(px), y0f = floorf(py);
            const float fx = px - x0f, fy = py - y0f;
            const int x0 = (int)x0f, y0 = (int)y0f;
            const int xb = min(max(x0, 0), Ww - 2);
            const int yb = min(max(y0, 0), Hh - 2);
            const bool xin = (x0 >= 0) & (x0 <= Ww - 2);
            const bool yin = (y0 >= 0) & (y0 <= Hh - 2);
            // weights for loaded columns {xb, xb+1} / rows {yb, yb+1}, OOB folded to 0
            wxA[a] = xin ? (1.f - fx) : ((x0 == -1)     ? fx        : 0.f);
            wxB[a] = xin ? fx         : ((x0 == Ww - 1) ? (1.f - fx) : 0.f);
            wyA[a] = yin ? (1.f - fy) : ((y0 == -1)     ? fy        : 0.f);
            wyB[a] = yin ? fy         : ((y0 == Hh - 1) ? (1.f - fy) : 0.f);
            offp[a] = yb * Ww + xb;
        }
    }

    const float* xb0 = x + (size_t)s * CHW;

    // ---- pass 1: agent0 direct load -> regs; agents 1..4 gather -> LDS bf16 ----
    float f0[CPG];
    float dj0 = 0.f, dj1 = 0.f, dj2 = 0.f, dj3 = 0.f, dj4 = 0.f;
#pragma unroll
    for (int k = 0; k < CPG; ++k) {
        const float* pc = xb0 + (size_t)(cbase + k) * HW;
        const float v0 = pc[p];                   // identity warp: exact
        f0[k] = v0;
        dj0 = fmaf(v0, v0, dj0);
        ushort4 pk = {0, 0, 0, 0};
        if (N > 1) {
            const float* q = pc + (size_t)1 * CHW + offp[0];
            const F2 r0 = *(const F2*)q; const F2 r1 = *(const F2*)(q + Ww);
            const float v = wyA[0] * (wxA[0] * r0.x + wxB[0] * r0.y)
                          + wyB[0] * (wxA[0] * r1.x + wxB[0] * r1.y);
            dj1 = fmaf(v0, v, dj1); pk.x = f2bf(v);
        }
        if (N > 2) {
            const float* q = pc + (size_t)2 * CHW + offp[1];
            const F2 r0 = *(const F2*)q; const F2 r1 = *(const F2*)(q + Ww);
            const float v = wyA[1] * (wxA[1] * r0.x + wxB[1] * r0.y)
                          + wyB[1] * (wxA[1] * r1.x + wxB[1] * r1.y);
            dj2 = fmaf(v0, v, dj2); pk.y = f2bf(v);
        }
        if (N > 3) {
            const float* q = pc + (size_t)3 * CHW + offp[2];
            const F2 r0 = *(const F2*)q; const F2 r1 = *(const F2*)(q + Ww);
            const float v = wyA[2] * (wxA[2] * r0.x + wxB[2] * r0.y)
                          + wyB[2] * (wxA[2] * r1.x + wxB[2] * r1.y);
            dj3 = fmaf(v0, v, dj3); pk.z = f2bf(v);
        }
        if (N > 4) {
            const float* q = pc + (size_t)4 * CHW + offp[3];
            const F2 r0 = *(const F2*)q; const F2 r1 = *(const F2*)(q + Ww);
            const float v = wyA[3] * (wxA[3] * r0.x + wxB[3] * r0.y)
                          + wyB[3] * (wxA[3] * r1.x + wxB[3] * r1.y);
            dj4 = fmaf(v0, v, dj4); pk.w = f2bf(v);
        }
        feat[cbase + k][pix] = pk;
    }

    // ---- dot reduce: 4 subgroups via shuffle, 8 waves via LDS ----
    float dj[5] = {dj0, dj1, dj2, dj3, dj4};
#pragma unroll
    for (int j = 0; j < 5; ++j) {
        dj[j] += __shfl_xor(dj[j], 16);
        dj[j] += __shfl_xor(dj[j], 32);
    }
    if (sub == 0) {
#pragma unroll
        for (int j = 0; j < 5; ++j) dl[wv][j][pix] = dj[j];
    }
    __syncthreads();

    // ---- softmax over j (per pixel, redundantly per thread) ----
    float e0, e1, e2, e3, e4;
    {
        float sc[5];
#pragma unroll
        for (int j = 0; j < 5; ++j) {
            float t = 0.f;
#pragma unroll
            for (int wvi = 0; wvi < 8; ++wvi) t += dl[wvi][j][pix];
            sc[j] = t * (1.0f / 16.0f);       // * 1/sqrt(C)
        }
        float m = sc[0];
        if (N > 1) m = fmaxf(m, sc[1]);
        if (N > 2) m = fmaxf(m, sc[2]);
        if (N > 3) m = fmaxf(m, sc[3]);
        if (N > 4) m = fmaxf(m, sc[4]);
        e0 = __expf(sc[0] - m);
        e1 = (N > 1) ? __expf(sc[1] - m) : 0.f;
        e2 = (N > 2) ? __expf(sc[2] - m) : 0.f;
        e3 = (N > 3) ? __expf(sc[3] - m) : 0.f;
        e4 = (N > 4) ? __expf(sc[4] - m) : 0.f;
        const float inv = 1.0f / (e0 + e1 + e2 + e3 + e4);
        e0 *= inv; e1 *= inv; e2 *= inv; e3 *= inv; e4 *= inv;
    }

    // ---- pass 2: weighted sum from regs + LDS, streamed out ----
    float* ob = out + (size_t)b * CHW + p;
#pragma unroll
    for (int k = 0; k < CPG; ++k) {
        const ushort4 u = feat[cbase + k][pix];
        float acc = e0 * f0[k];
        acc = fmaf(e1, bf2f(u.x), acc);
        acc = fmaf(e2, bf2f(u.y), acc);
        acc = fmaf(e3, bf2f(u.z), acc);
        acc = fmaf(e4, bf2f(u.w), acc);
        __builtin_nontemporal_store(acc, ob + (size_t)(cbase + k) * HW);
    }
}

extern "C" void kernel_launch(void* const* d_in, const int* in_sizes, int n_in,
                              void* d_out, int out_size, void* d_ws, size_t ws_size,
                              hipStream_t stream) {
    const float* x    = (const float*)d_in[0];
    // d_in[1] = rm (unused by reference output), d_in[2] = record_len (constant)
    const float* tmat = (const float*)d_in[3];
    float* out = (float*)d_out;
    dim3 grid(4 * TILES);
    dim3 block(NTHR);
    hipLaunchKernelGGL(atten_fused, grid, block, 0, stream, x, tmat, out);
}